// Round 4
// baseline (195.805 us; speedup 1.0000x reference)
//
#include <hip/hip_runtime.h>
#include <hip/hip_bf16.h>

#define N_NODES 8192
#define N_EDGES 524288
#define TOT_EDGES (N_EDGES + N_NODES)   /* 532480 */
#define IN_DIM 256
#define HID1 128
#define HID2 64
#define DC 128   /* combined [mu | lv] feature dim */

typedef __attribute__((ext_vector_type(8))) short bf16x8;
typedef __attribute__((ext_vector_type(4))) float f32x4;
typedef __attribute__((ext_vector_type(4))) int   i32x4;
typedef __attribute__((ext_vector_type(4))) unsigned short u16x4;

// ---------------- D1: fused xcvt (blocks 0..2047) + wcomb (2048..2175) + ws-zero (2176..2200) ----------------

__global__ __launch_bounds__(256) void k_pre(const float* __restrict__ x, unsigned short* __restrict__ xbf,
                                             const float* __restrict__ W1, const float* __restrict__ W2,
                                             const float* __restrict__ Wmu, const float* __restrict__ Wlv,
                                             const float* __restrict__ b1, const float* __restrict__ b2,
                                             unsigned short* __restrict__ WcT, float* __restrict__ cvec,
                                             float* __restrict__ zbase){
    int b = blockIdx.x, t = threadIdx.x;
    if (b < 2048){
        int g = (b*256 + t)*4;
        f32x4 v = *(const f32x4*)(x + g);
        u16x4 o;
        #pragma unroll
        for (int j=0;j<4;j++){ __hip_bfloat16 h = __float2bfloat16(v[j]); o[j] = *(unsigned short*)&h; }
        *(u16x4*)(xbf + g) = o;
    } else if (b < 2176){
        int r = (b - 2048)*2 + (t >> 7);    // 0..255
        int j = t & 127;                    // wave-uniform Wsel select
        const float* Wsel = (j < 64) ? Wmu : Wlv;
        int jj = j & 63;
        float acc = 0.f;
        for (int k=0;k<HID1;k++){
            acc += W1[r*HID1+k] * Wsel[k*HID2+jj] + W2[r*HID1+k] * Wsel[(HID1+k)*HID2+jj];
        }
        __hip_bfloat16 h = __float2bfloat16(acc);
        WcT[(size_t)j*IN_DIM + r] = *(unsigned short*)&h;
        if (r == 0){
            float c = 0.f;
            for (int k=0;k<HID1;k++){
                c += b1[k]*Wsel[k*HID2+jj] + b2[k]*Wsel[(HID1+k)*HID2+jj];
            }
            cvec[j] = c;
        }
    } else {
        // zero 102400 B of ws (deg + rowPtr + fill): 25 blocks x 256 thr x 16 B
        ((f32x4*)zbase)[(b-2176)*256 + t] = (f32x4){0.f,0.f,0.f,0.f};
    }
}

// ---------------- D2: degree count ----------------

__global__ __launch_bounds__(256) void k_count(const int* __restrict__ ei, int* __restrict__ deg){
    int e = blockIdx.x*256 + threadIdx.x;
    if (e >= TOT_EDGES) return;
    int r = (e < N_EDGES) ? ei[e] : (e - N_EDGES);
    atomicAdd(&deg[r], 1);
}

// ---------------- D3: fused scan+dinv (block 0) + gemm_u (blocks 1..256) ----------------

__global__ __launch_bounds__(256) void k_scan_gemm(const int* __restrict__ deg, int* __restrict__ rowPtr,
                                                   float* __restrict__ dinv,
                                                   const unsigned short* __restrict__ xbf,
                                                   const unsigned short* __restrict__ WcT,
                                                   float* __restrict__ U){
    __shared__ int lds[256];
    int t = threadIdx.x;
    if (blockIdx.x == 0){
        // prefix scan of 8192 degrees, 32 per thread, vectorized
        int base = t*32;
        const i32x4* dp = (const i32x4*)(deg + base);
        int s = 0;
        #pragma unroll
        for (int k=0;k<8;k++){ i32x4 q = dp[k]; s += q[0]+q[1]+q[2]+q[3]; }
        lds[t] = s;
        __syncthreads();
        for (int off=1; off<256; off<<=1){
            int v = (t >= off) ? lds[t-off] : 0;
            __syncthreads();
            lds[t] += v;
            __syncthreads();
        }
        int run = (t==0) ? 0 : lds[t-1];
        #pragma unroll
        for (int k=0;k<8;k++){
            i32x4 q = dp[k];
            i32x4 rp; f32x4 dv;
            #pragma unroll
            for (int j=0;j<4;j++){
                rp[j] = run;
                dv[j] = (q[j] > 0) ? rsqrtf((float)q[j]) : 0.f;
                run += q[j];
            }
            *(i32x4*)(rowPtr + base + k*4) = rp;
            *(f32x4*)(dinv   + base + k*4) = dv;
        }
        if (t == 255) rowPtr[N_NODES] = run;
    } else {
        // U = x @ Wc via bf16 MFMA. Block tile 32 x 128 (4 waves of 32x32).
        int l  = t & 63;
        int w  = t >> 6;
        int Ibase = (blockIdx.x - 1)*32;
        int Jbase = w*32;
        int lr = l & 15;
        int kg = l >> 4;
        f32x4 acc[2][2];
        #pragma unroll
        for (int mt=0;mt<2;mt++)
            #pragma unroll
            for (int nt=0;nt<2;nt++) acc[mt][nt] = (f32x4){0.f,0.f,0.f,0.f};
        #pragma unroll
        for (int kc=0; kc<IN_DIM/32; kc++){
            bf16x8 a[2], bb[2];
            #pragma unroll
            for (int mt=0;mt<2;mt++)
                a[mt] = *(const bf16x8*)(xbf + (size_t)(Ibase+mt*16+lr)*IN_DIM + kc*32 + kg*8);
            #pragma unroll
            for (int nt=0;nt<2;nt++)
                bb[nt] = *(const bf16x8*)(WcT + (size_t)(Jbase+nt*16+lr)*IN_DIM + kc*32 + kg*8);
            #pragma unroll
            for (int mt=0;mt<2;mt++)
                #pragma unroll
                for (int nt=0;nt<2;nt++)
                    acc[mt][nt] = __builtin_amdgcn_mfma_f32_16x16x32_bf16(a[mt], bb[nt], acc[mt][nt], 0, 0, 0);
        }
        #pragma unroll
        for (int mt=0;mt<2;mt++)
            #pragma unroll
            for (int r=0;r<4;r++){
                int grow = Ibase + mt*16 + kg*4 + r;
                #pragma unroll
                for (int nt=0;nt<2;nt++)
                    U[(size_t)grow*DC + Jbase + nt*16 + lr] = acc[mt][nt][r];
            }
    }
}

// ---------------- D4: CSR fill ----------------

__global__ __launch_bounds__(256) void k_fill(const int* __restrict__ ei, const int* __restrict__ rowPtr,
                                              int* __restrict__ fill, int* __restrict__ csr_col){
    int e = blockIdx.x*256 + threadIdx.x;
    if (e >= TOT_EDGES) return;
    int r, c;
    if (e < N_EDGES){ r = ei[e]; c = ei[N_EDGES + e]; }
    else            { r = e - N_EDGES; c = r; }
    int pos = rowPtr[r] + atomicAdd(&fill[r], 1);
    csr_col[pos] = c;
}

// ---------------- D5: SpMM  OUT = Â * IN  (256 thr: 8 edges x 32 col-lanes per iter) ----------------

__global__ __launch_bounds__(256) void k_spmm(const float* __restrict__ IN, const int* __restrict__ rowPtr,
                                              const int* __restrict__ csr_col, const float* __restrict__ dinv,
                                              float* __restrict__ OUT){
    int i = blockIdx.x;
    int tid = threadIdx.x;
    int lane = tid & 31, eg = tid >> 5;
    int beg = rowPtr[i], end = rowPtr[i+1];
    __shared__ int   s_col[128];
    __shared__ float s_w[128];
    __shared__ f32x4 s_red[224];
    f32x4 acc = (f32x4){0.f,0.f,0.f,0.f};
    for (int base = beg; base < end; base += 128){
        int nch  = min(128, end - base);
        int nchp = (nch + 7) & ~7;
        if (tid < 128){
            if (tid < nch){ int c = csr_col[base + tid]; s_col[tid] = c; s_w[tid] = dinv[c]; }
            else if (tid < nchp){ s_col[tid] = 0; s_w[tid] = 0.f; }
        }
        __syncthreads();
        for (int e = eg; e < nchp; e += 8){
            int c = s_col[e]; float wgt = s_w[e];
            f32x4 v = *(const f32x4*)(IN + (size_t)c*DC + lane*4);
            #pragma unroll
            for (int j=0;j<4;j++) acc[j] += wgt * v[j];
        }
        __syncthreads();
    }
    if (tid >= 32) s_red[tid-32] = acc;
    __syncthreads();
    if (tid < 32){
        f32x4 r = acc;
        #pragma unroll
        for (int g=0; g<7; g++){
            f32x4 tt = s_red[tid + g*32];
            #pragma unroll
            for (int j=0;j<4;j++) r[j] += tt[j];
        }
        float di = dinv[i];
        #pragma unroll
        for (int j=0;j<4;j++) r[j] *= di;
        *(f32x4*)(OUT + (size_t)i*DC + tid*4) = r;
    }
}

// ---------------- D6: second SpMM + rank-1 bias + outputs (mu f32, lv f32, mu bf16) ----------------

__global__ __launch_bounds__(256) void k_spmm_out(const float* __restrict__ T, const int* __restrict__ rowPtr,
                                                  const int* __restrict__ csr_col, const float* __restrict__ dinv,
                                                  const float* __restrict__ cvec,
                                                  const float* __restrict__ bmu, const float* __restrict__ blv,
                                                  float* __restrict__ outMu, float* __restrict__ outLv,
                                                  unsigned short* __restrict__ muBf){
    int i = blockIdx.x;
    int tid = threadIdx.x;
    int lane = tid & 31, eg = tid >> 5;
    int beg = rowPtr[i], end = rowPtr[i+1];
    __shared__ int   s_col[128];
    __shared__ float s_w[128];
    __shared__ f32x4 s_red[224];
    __shared__ float s_wred[8];
    f32x4 acc = (f32x4){0.f,0.f,0.f,0.f};
    float wsum = 0.f;
    for (int base = beg; base < end; base += 128){
        int nch  = min(128, end - base);
        int nchp = (nch + 7) & ~7;
        if (tid < 128){
            if (tid < nch){ int c = csr_col[base + tid]; s_col[tid] = c; s_w[tid] = dinv[c]; }
            else if (tid < nchp){ s_col[tid] = 0; s_w[tid] = 0.f; }
        }
        __syncthreads();
        for (int e = eg; e < nchp; e += 8){
            int c = s_col[e]; float wgt = s_w[e];
            wsum += wgt;
            f32x4 v = *(const f32x4*)(T + (size_t)c*DC + lane*4);
            #pragma unroll
            for (int j=0;j<4;j++) acc[j] += wgt * v[j];
        }
        __syncthreads();
    }
    if (tid >= 32) s_red[tid-32] = acc;
    if (lane == 0) s_wred[eg] = wsum;
    __syncthreads();
    if (tid < 32){
        f32x4 r = acc;
        #pragma unroll
        for (int g=0; g<7; g++){
            f32x4 tt = s_red[tid + g*32];
            #pragma unroll
            for (int j=0;j<4;j++) r[j] += tt[j];
        }
        float di = dinv[i];
        float sv = di * (s_wred[0]+s_wred[1]+s_wred[2]+s_wred[3]
                        +s_wred[4]+s_wred[5]+s_wred[6]+s_wred[7]);   // (Â·1)_i
        f32x4 cv = *(const f32x4*)(cvec + tid*4);
        f32x4 val;
        if (tid < 16){
            f32x4 bb = *(const f32x4*)(bmu + tid*4);
            #pragma unroll
            for (int j=0;j<4;j++) val[j] = di*r[j] + sv*cv[j] + bb[j];
            *(f32x4*)(outMu + (size_t)i*HID2 + tid*4) = val;
            u16x4 o;
            #pragma unroll
            for (int j=0;j<4;j++){ __hip_bfloat16 h = __float2bfloat16(val[j]); o[j] = *(unsigned short*)&h; }
            *(u16x4*)(muBf + (size_t)i*HID2 + tid*4) = o;
        } else {
            f32x4 bb = *(const f32x4*)(blv + (tid-16)*4);
            #pragma unroll
            for (int j=0;j<4;j++) val[j] = di*r[j] + sv*cv[j] + bb[j];
            *(f32x4*)(outLv + (size_t)i*HID2 + (tid-16)*4) = val;
        }
    }
}

// ---------------- D7: adj = sigmoid(mu @ mu^T) via bf16 MFMA 16x16x32 ----------------

__global__ __launch_bounds__(256) void k_adj(const unsigned short* __restrict__ mu, float* __restrict__ adj){
    int l  = threadIdx.x & 63;
    int w  = threadIdx.x >> 6;
    int wr = w >> 1, wc = w & 1;
    int Ibase = blockIdx.y*128 + wr*64;
    int Jbase = blockIdx.x*128 + wc*64;
    int lr = l & 15;
    int kg = l >> 4;

    bf16x8 afr[4][2], bfr[4][2];
    #pragma unroll
    for (int mt=0; mt<4; mt++){
        const unsigned short* p = mu + (size_t)(Ibase + mt*16 + lr)*HID2 + kg*8;
        afr[mt][0] = *(const bf16x8*)(p);
        afr[mt][1] = *(const bf16x8*)(p + 32);
    }
    #pragma unroll
    for (int nt=0; nt<4; nt++){
        const unsigned short* p = mu + (size_t)(Jbase + nt*16 + lr)*HID2 + kg*8;
        bfr[nt][0] = *(const bf16x8*)(p);
        bfr[nt][1] = *(const bf16x8*)(p + 32);
    }

    f32x4 acc[4][4];
    #pragma unroll
    for (int mt=0; mt<4; mt++)
        #pragma unroll
        for (int nt=0; nt<4; nt++)
            acc[mt][nt] = (f32x4){0.f,0.f,0.f,0.f};

    #pragma unroll
    for (int kc=0; kc<2; kc++)
        #pragma unroll
        for (int mt=0; mt<4; mt++)
            #pragma unroll
            for (int nt=0; nt<4; nt++)
                acc[mt][nt] = __builtin_amdgcn_mfma_f32_16x16x32_bf16(afr[mt][kc], bfr[nt][kc], acc[mt][nt], 0, 0, 0);

    #pragma unroll
    for (int mt=0; mt<4; mt++){
        #pragma unroll
        for (int r=0; r<4; r++){
            int grow = Ibase + mt*16 + kg*4 + r;
            float* dst = adj + (size_t)grow*N_NODES + Jbase;
            #pragma unroll
            for (int nt=0; nt<4; nt++){
                float v = acc[mt][nt][r];
                __builtin_nontemporal_store(1.f/(1.f + __expf(-v)), dst + nt*16 + lr);
            }
        }
    }
}

// ---------------- launch ----------------

extern "C" void kernel_launch(void* const* d_in, const int* in_sizes, int n_in,
                              void* d_out, int out_size, void* d_ws, size_t ws_size,
                              hipStream_t stream){
    const float* x   = (const float*)d_in[0];
    const int*   ei  = (const int*)  d_in[1];
    const float* W1  = (const float*)d_in[2];
    const float* b1  = (const float*)d_in[3];
    const float* W2  = (const float*)d_in[4];
    const float* b2  = (const float*)d_in[5];
    const float* Wmu = (const float*)d_in[6];
    const float* bmu = (const float*)d_in[7];
    const float* Wlv = (const float*)d_in[8];
    const float* blv = (const float*)d_in[9];

    char* ws = (char*)d_ws;
    int*   deg    = (int*)  (ws + 0);        // 32768 B
    int*   rowPtr = (int*)  (ws + 32768);    // 8193 ints (+pad)
    int*   fill   = (int*)  (ws + 69632);    // 32768 B, ends at 102400
    float* dinv   = (float*)(ws + 102400);   // 32768 B
    int*   csrcol = (int*)  (ws + 135168);   // 2,129,920 B -> 2,265,088
    unsigned short* WcT = (unsigned short*)(ws + 2265088); // 64 KB -> 2,330,624
    float* cvec   = (float*)(ws + 2330624);  // 512 B -> 2,331,136
    unsigned short* muBf = (unsigned short*)(ws + 2331136); // 1 MB -> 3,379,712
    unsigned short* xbf  = (unsigned short*)(ws + 3379712); // 4 MB -> 7,574,016

    float* adj   = (float*)d_out;
    float* outMu = adj + (size_t)N_NODES*N_NODES;
    float* outLv = outMu + (size_t)N_NODES*HID2;

    // U, T dead before k_adj -> stage inside adj region (268 MB)
    float* U = adj;                           // 4 MB
    float* T = adj + (size_t)4*1024*1024;     // disjoint (16 MB byte offset)

    k_pre      <<<2201, 256, 0, stream>>>(x, xbf, W1, W2, Wmu, Wlv, b1, b2, WcT, cvec, (float*)ws);
    k_count    <<<2080, 256, 0, stream>>>(ei, deg);
    k_scan_gemm<<< 257, 256, 0, stream>>>(deg, rowPtr, dinv, xbf, WcT, U);
    k_fill     <<<2080, 256, 0, stream>>>(ei, rowPtr, fill, csrcol);
    k_spmm     <<<N_NODES, 256, 0, stream>>>(U, rowPtr, csrcol, dinv, T);
    k_spmm_out <<<N_NODES, 256, 0, stream>>>(T, rowPtr, csrcol, dinv, cvec, bmu, blv,
                                             outMu, outLv, muBf);
    k_adj      <<<dim3(N_NODES/128, N_NODES/128), 256, 0, stream>>>(muBf, adj);
}

// Round 5
// 184.020 us; speedup vs baseline: 1.0640x; 1.0640x over previous
//
#include <hip/hip_runtime.h>
#include <hip/hip_bf16.h>

#define N_NODES 8192
#define N_EDGES 524288
#define TOT_EDGES (N_EDGES + N_NODES)   /* 532480 */
#define IN_DIM 256
#define HID1 128
#define HID2 64
#define DC 128   /* combined [mu | lv] feature dim */

typedef __attribute__((ext_vector_type(8))) short bf16x8;
typedef __attribute__((ext_vector_type(4))) float f32x4;
typedef __attribute__((ext_vector_type(4))) int   i32x4;
typedef __attribute__((ext_vector_type(4))) unsigned short u16x4;

// ---------------- D1: fused xcvt (blocks 0..2047) + wcomb (2048..2175) + ws-zero (2176..2200) ----------------

__global__ __launch_bounds__(256) void k_pre(const float* __restrict__ x, unsigned short* __restrict__ xbf,
                                             const float* __restrict__ W1, const float* __restrict__ W2,
                                             const float* __restrict__ Wmu, const float* __restrict__ Wlv,
                                             const float* __restrict__ b1, const float* __restrict__ b2,
                                             unsigned short* __restrict__ WcT, float* __restrict__ cvec,
                                             float* __restrict__ zbase){
    int b = blockIdx.x, t = threadIdx.x;
    if (b < 2048){
        int g = (b*256 + t)*4;
        f32x4 v = *(const f32x4*)(x + g);
        u16x4 o;
        #pragma unroll
        for (int j=0;j<4;j++){ __hip_bfloat16 h = __float2bfloat16(v[j]); o[j] = *(unsigned short*)&h; }
        *(u16x4*)(xbf + g) = o;
    } else if (b < 2176){
        int r = (b - 2048)*2 + (t >> 7);    // 0..255
        int j = t & 127;                    // wave-uniform Wsel select
        const float* Wsel = (j < 64) ? Wmu : Wlv;
        int jj = j & 63;
        float acc = 0.f;
        for (int k=0;k<HID1;k++){
            acc += W1[r*HID1+k] * Wsel[k*HID2+jj] + W2[r*HID1+k] * Wsel[(HID1+k)*HID2+jj];
        }
        __hip_bfloat16 h = __float2bfloat16(acc);
        WcT[(size_t)j*IN_DIM + r] = *(unsigned short*)&h;
        if (r == 0){
            float c = 0.f;
            for (int k=0;k<HID1;k++){
                c += b1[k]*Wsel[k*HID2+jj] + b2[k]*Wsel[(HID1+k)*HID2+jj];
            }
            cvec[j] = c;
        }
    } else {
        // zero 102400 B of ws (deg + rowPtr + fill): 25 blocks x 256 thr x 16 B
        ((f32x4*)zbase)[(b-2176)*256 + t] = (f32x4){0.f,0.f,0.f,0.f};
    }
}

// ---------------- D2: degree count ----------------

__global__ __launch_bounds__(256) void k_count(const int* __restrict__ ei, int* __restrict__ deg){
    int e = blockIdx.x*256 + threadIdx.x;
    if (e >= TOT_EDGES) return;
    int r = (e < N_EDGES) ? ei[e] : (e - N_EDGES);
    atomicAdd(&deg[r], 1);
}

// ---------------- D3: fused scan+dinv (block 0) + gemm_u (blocks 1..256) ----------------

__global__ __launch_bounds__(256) void k_scan_gemm(const int* __restrict__ deg, int* __restrict__ rowPtr,
                                                   float* __restrict__ dinv,
                                                   const unsigned short* __restrict__ xbf,
                                                   const unsigned short* __restrict__ WcT,
                                                   float* __restrict__ U){
    __shared__ int lds[256];
    int t = threadIdx.x;
    if (blockIdx.x == 0){
        // prefix scan of 8192 degrees, 32 per thread, vectorized
        int base = t*32;
        const i32x4* dp = (const i32x4*)(deg + base);
        int s = 0;
        #pragma unroll
        for (int k=0;k<8;k++){ i32x4 q = dp[k]; s += q[0]+q[1]+q[2]+q[3]; }
        lds[t] = s;
        __syncthreads();
        for (int off=1; off<256; off<<=1){
            int v = (t >= off) ? lds[t-off] : 0;
            __syncthreads();
            lds[t] += v;
            __syncthreads();
        }
        int run = (t==0) ? 0 : lds[t-1];
        #pragma unroll
        for (int k=0;k<8;k++){
            i32x4 q = dp[k];
            i32x4 rp; f32x4 dv;
            #pragma unroll
            for (int j=0;j<4;j++){
                rp[j] = run;
                dv[j] = (q[j] > 0) ? rsqrtf((float)q[j]) : 0.f;
                run += q[j];
            }
            *(i32x4*)(rowPtr + base + k*4) = rp;
            *(f32x4*)(dinv   + base + k*4) = dv;
        }
        if (t == 255) rowPtr[N_NODES] = run;
    } else {
        // U = x @ Wc via bf16 MFMA. Block tile 32 x 128 (4 waves of 32x32).
        int l  = t & 63;
        int w  = t >> 6;
        int Ibase = (blockIdx.x - 1)*32;
        int Jbase = w*32;
        int lr = l & 15;
        int kg = l >> 4;
        f32x4 acc[2][2];
        #pragma unroll
        for (int mt=0;mt<2;mt++)
            #pragma unroll
            for (int nt=0;nt<2;nt++) acc[mt][nt] = (f32x4){0.f,0.f,0.f,0.f};
        #pragma unroll
        for (int kc=0; kc<IN_DIM/32; kc++){
            bf16x8 a[2], bb[2];
            #pragma unroll
            for (int mt=0;mt<2;mt++)
                a[mt] = *(const bf16x8*)(xbf + (size_t)(Ibase+mt*16+lr)*IN_DIM + kc*32 + kg*8);
            #pragma unroll
            for (int nt=0;nt<2;nt++)
                bb[nt] = *(const bf16x8*)(WcT + (size_t)(Jbase+nt*16+lr)*IN_DIM + kc*32 + kg*8);
            #pragma unroll
            for (int mt=0;mt<2;mt++)
                #pragma unroll
                for (int nt=0;nt<2;nt++)
                    acc[mt][nt] = __builtin_amdgcn_mfma_f32_16x16x32_bf16(a[mt], bb[nt], acc[mt][nt], 0, 0, 0);
        }
        #pragma unroll
        for (int mt=0;mt<2;mt++)
            #pragma unroll
            for (int r=0;r<4;r++){
                int grow = Ibase + mt*16 + kg*4 + r;
                #pragma unroll
                for (int nt=0;nt<2;nt++)
                    U[(size_t)grow*DC + Jbase + nt*16 + lr] = acc[mt][nt][r];
            }
    }
}

// ---------------- D4: CSR fill ----------------

__global__ __launch_bounds__(256) void k_fill(const int* __restrict__ ei, const int* __restrict__ rowPtr,
                                              int* __restrict__ fill, int* __restrict__ csr_col){
    int e = blockIdx.x*256 + threadIdx.x;
    if (e >= TOT_EDGES) return;
    int r, c;
    if (e < N_EDGES){ r = ei[e]; c = ei[N_EDGES + e]; }
    else            { r = e - N_EDGES; c = r; }
    int pos = rowPtr[r] + atomicAdd(&fill[r], 1);
    csr_col[pos] = c;
}

// ---------------- D5: SpMM  OUT = Â * IN  (256 thr: 8 edges x 32 col-lanes per iter) ----------------

__global__ __launch_bounds__(256) void k_spmm(const float* __restrict__ IN, const int* __restrict__ rowPtr,
                                              const int* __restrict__ csr_col, const float* __restrict__ dinv,
                                              float* __restrict__ OUT){
    int i = blockIdx.x;
    int tid = threadIdx.x;
    int lane = tid & 31, eg = tid >> 5;
    int beg = rowPtr[i], end = rowPtr[i+1];
    __shared__ int   s_col[128];
    __shared__ float s_w[128];
    __shared__ f32x4 s_red[224];
    f32x4 acc = (f32x4){0.f,0.f,0.f,0.f};
    for (int base = beg; base < end; base += 128){
        int nch  = min(128, end - base);
        int nchp = (nch + 7) & ~7;
        if (tid < 128){
            if (tid < nch){ int c = csr_col[base + tid]; s_col[tid] = c; s_w[tid] = dinv[c]; }
            else if (tid < nchp){ s_col[tid] = 0; s_w[tid] = 0.f; }
        }
        __syncthreads();
        for (int e = eg; e < nchp; e += 8){
            int c = s_col[e]; float wgt = s_w[e];
            f32x4 v = *(const f32x4*)(IN + (size_t)c*DC + lane*4);
            #pragma unroll
            for (int j=0;j<4;j++) acc[j] += wgt * v[j];
        }
        __syncthreads();
    }
    if (tid >= 32) s_red[tid-32] = acc;
    __syncthreads();
    if (tid < 32){
        f32x4 r = acc;
        #pragma unroll
        for (int g=0; g<7; g++){
            f32x4 tt = s_red[tid + g*32];
            #pragma unroll
            for (int j=0;j<4;j++) r[j] += tt[j];
        }
        float di = dinv[i];
        #pragma unroll
        for (int j=0;j<4;j++) r[j] *= di;
        *(f32x4*)(OUT + (size_t)i*DC + tid*4) = r;
    }
}

// ---------------- D6: second SpMM + rank-1 bias + outputs (mu f32, lv f32, mu bf16) ----------------

__global__ __launch_bounds__(256) void k_spmm_out(const float* __restrict__ T, const int* __restrict__ rowPtr,
                                                  const int* __restrict__ csr_col, const float* __restrict__ dinv,
                                                  const float* __restrict__ cvec,
                                                  const float* __restrict__ bmu, const float* __restrict__ blv,
                                                  float* __restrict__ outMu, float* __restrict__ outLv,
                                                  unsigned short* __restrict__ muBf){
    int i = blockIdx.x;
    int tid = threadIdx.x;
    int lane = tid & 31, eg = tid >> 5;
    int beg = rowPtr[i], end = rowPtr[i+1];
    __shared__ int   s_col[128];
    __shared__ float s_w[128];
    __shared__ f32x4 s_red[224];
    __shared__ float s_wred[8];
    f32x4 acc = (f32x4){0.f,0.f,0.f,0.f};
    float wsum = 0.f;
    for (int base = beg; base < end; base += 128){
        int nch  = min(128, end - base);
        int nchp = (nch + 7) & ~7;
        if (tid < 128){
            if (tid < nch){ int c = csr_col[base + tid]; s_col[tid] = c; s_w[tid] = dinv[c]; }
            else if (tid < nchp){ s_col[tid] = 0; s_w[tid] = 0.f; }
        }
        __syncthreads();
        for (int e = eg; e < nchp; e += 8){
            int c = s_col[e]; float wgt = s_w[e];
            wsum += wgt;
            f32x4 v = *(const f32x4*)(T + (size_t)c*DC + lane*4);
            #pragma unroll
            for (int j=0;j<4;j++) acc[j] += wgt * v[j];
        }
        __syncthreads();
    }
    if (tid >= 32) s_red[tid-32] = acc;
    if (lane == 0) s_wred[eg] = wsum;
    __syncthreads();
    if (tid < 32){
        f32x4 r = acc;
        #pragma unroll
        for (int g=0; g<7; g++){
            f32x4 tt = s_red[tid + g*32];
            #pragma unroll
            for (int j=0;j<4;j++) r[j] += tt[j];
        }
        float di = dinv[i];
        float sv = di * (s_wred[0]+s_wred[1]+s_wred[2]+s_wred[3]
                        +s_wred[4]+s_wred[5]+s_wred[6]+s_wred[7]);   // (Â·1)_i
        f32x4 cv = *(const f32x4*)(cvec + tid*4);
        f32x4 val;
        if (tid < 16){
            f32x4 bb = *(const f32x4*)(bmu + tid*4);
            #pragma unroll
            for (int j=0;j<4;j++) val[j] = di*r[j] + sv*cv[j] + bb[j];
            *(f32x4*)(outMu + (size_t)i*HID2 + tid*4) = val;
            u16x4 o;
            #pragma unroll
            for (int j=0;j<4;j++){ __hip_bfloat16 h = __float2bfloat16(val[j]); o[j] = *(unsigned short*)&h; }
            *(u16x4*)(muBf + (size_t)i*HID2 + tid*4) = o;
        } else {
            f32x4 bb = *(const f32x4*)(blv + (tid-16)*4);
            #pragma unroll
            for (int j=0;j<4;j++) val[j] = di*r[j] + sv*cv[j] + bb[j];
            *(f32x4*)(outLv + (size_t)i*HID2 + (tid-16)*4) = val;
        }
    }
}

// ---------------- D7: adj = sigmoid(mu @ mu^T) via bf16 MFMA, LDS-transposed coalesced epilogue ----------------
// Block: 256 thr = 4 waves (2x2 of 64x64). Epilogue: stage 64 rows at a time in LDS,
// then all 256 threads store f32x4 (512B-contiguous per 32-lane group).

__global__ __launch_bounds__(256) void k_adj(const unsigned short* __restrict__ mu, float* __restrict__ adj){
    int t  = threadIdx.x;
    int l  = t & 63;
    int w  = t >> 6;
    int wr = w >> 1, wc = w & 1;
    int Ibase = blockIdx.y*128 + wr*64;
    int Jbase0 = blockIdx.x*128;
    int Jbase = Jbase0 + wc*64;
    int lr = l & 15;
    int kg = l >> 4;

    bf16x8 afr[4][2], bfr[4][2];
    #pragma unroll
    for (int mt=0; mt<4; mt++){
        const unsigned short* p = mu + (size_t)(Ibase + mt*16 + lr)*HID2 + kg*8;
        afr[mt][0] = *(const bf16x8*)(p);
        afr[mt][1] = *(const bf16x8*)(p + 32);
    }
    #pragma unroll
    for (int nt=0; nt<4; nt++){
        const unsigned short* p = mu + (size_t)(Jbase + nt*16 + lr)*HID2 + kg*8;
        bfr[nt][0] = *(const bf16x8*)(p);
        bfr[nt][1] = *(const bf16x8*)(p + 32);
    }

    f32x4 acc[4][4];
    #pragma unroll
    for (int mt=0; mt<4; mt++)
        #pragma unroll
        for (int nt=0; nt<4; nt++)
            acc[mt][nt] = (f32x4){0.f,0.f,0.f,0.f};

    #pragma unroll
    for (int kc=0; kc<2; kc++)
        #pragma unroll
        for (int mt=0; mt<4; mt++)
            #pragma unroll
            for (int nt=0; nt<4; nt++)
                acc[mt][nt] = __builtin_amdgcn_mfma_f32_16x16x32_bf16(afr[mt][kc], bfr[nt][kc], acc[mt][nt], 0, 0, 0);

    // --- epilogue: two 64-row passes through LDS, wide coalesced stores ---
    __shared__ float tile[64][132];   // +4 pad: keeps 16B alignment, breaks bank alias
    int rowBlockBase = blockIdx.y*128;
    #pragma unroll
    for (int p=0; p<2; p++){
        if (wr == p){
            // sigmoid + scatter into LDS. C/D: col = lane&15, row = (lane>>4)*4 + reg
            #pragma unroll
            for (int mt=0; mt<4; mt++)
                #pragma unroll
                for (int r=0; r<4; r++){
                    int row_local = mt*16 + kg*4 + r;          // 0..63
                    #pragma unroll
                    for (int nt=0; nt<4; nt++){
                        float v = acc[mt][nt][r];
                        tile[row_local][wc*64 + nt*16 + lr] = 1.f/(1.f + __expf(-v));
                    }
                }
        }
        __syncthreads();
        // 64 rows x 128 cols = 8192 floats; 8 reps x 256 thr x f32x4
        #pragma unroll
        for (int rep=0; rep<8; rep++){
            int row_r = rep*8 + (t >> 5);                      // 0..63
            int col   = (t & 31)*4;
            f32x4 v = *(const f32x4*)&tile[row_r][col];
            int grow = rowBlockBase + p*64 + row_r;
            __builtin_nontemporal_store(v, (f32x4*)(adj + (size_t)grow*N_NODES + Jbase0 + col));
        }
        __syncthreads();
    }
}

// ---------------- launch ----------------

extern "C" void kernel_launch(void* const* d_in, const int* in_sizes, int n_in,
                              void* d_out, int out_size, void* d_ws, size_t ws_size,
                              hipStream_t stream){
    const float* x   = (const float*)d_in[0];
    const int*   ei  = (const int*)  d_in[1];
    const float* W1  = (const float*)d_in[2];
    const float* b1  = (const float*)d_in[3];
    const float* W2  = (const float*)d_in[4];
    const float* b2  = (const float*)d_in[5];
    const float* Wmu = (const float*)d_in[6];
    const float* bmu = (const float*)d_in[7];
    const float* Wlv = (const float*)d_in[8];
    const float* blv = (const float*)d_in[9];

    char* ws = (char*)d_ws;
    int*   deg    = (int*)  (ws + 0);        // 32768 B
    int*   rowPtr = (int*)  (ws + 32768);    // 8193 ints (+pad)
    int*   fill   = (int*)  (ws + 69632);    // 32768 B, ends at 102400
    float* dinv   = (float*)(ws + 102400);   // 32768 B
    int*   csrcol = (int*)  (ws + 135168);   // 2,129,920 B -> 2,265,088
    unsigned short* WcT = (unsigned short*)(ws + 2265088); // 64 KB -> 2,330,624
    float* cvec   = (float*)(ws + 2330624);  // 512 B -> 2,331,136
    unsigned short* muBf = (unsigned short*)(ws + 2331136); // 1 MB -> 3,379,712
    unsigned short* xbf  = (unsigned short*)(ws + 3379712); // 4 MB -> 7,574,016

    float* adj   = (float*)d_out;
    float* outMu = adj + (size_t)N_NODES*N_NODES;
    float* outLv = outMu + (size_t)N_NODES*HID2;

    // U, T dead before k_adj -> stage inside adj region (268 MB)
    float* U = adj;                           // 4 MB
    float* T = adj + (size_t)4*1024*1024;     // disjoint (16 MB byte offset)

    k_pre      <<<2201, 256, 0, stream>>>(x, xbf, W1, W2, Wmu, Wlv, b1, b2, WcT, cvec, (float*)ws);
    k_count    <<<2080, 256, 0, stream>>>(ei, deg);
    k_scan_gemm<<< 257, 256, 0, stream>>>(deg, rowPtr, dinv, xbf, WcT, U);
    k_fill     <<<2080, 256, 0, stream>>>(ei, rowPtr, fill, csrcol);
    k_spmm     <<<N_NODES, 256, 0, stream>>>(U, rowPtr, csrcol, dinv, T);
    k_spmm_out <<<N_NODES, 256, 0, stream>>>(T, rowPtr, csrcol, dinv, cvec, bmu, blv,
                                             outMu, outLv, muBf);
    k_adj      <<<dim3(N_NODES/128, N_NODES/128), 256, 0, stream>>>(muBf, adj);
}

// Round 6
// 176.581 us; speedup vs baseline: 1.1089x; 1.0421x over previous
//
#include <hip/hip_runtime.h>
#include <hip/hip_bf16.h>

#define N_NODES 8192
#define N_EDGES 524288
#define TOT_EDGES (N_EDGES + N_NODES)   /* 532480 */
#define IN_DIM 256
#define HID1 128
#define HID2 64
#define DC 128   /* combined [mu | lv] feature dim */

typedef __attribute__((ext_vector_type(8))) short bf16x8;
typedef __attribute__((ext_vector_type(4))) float f32x4;
typedef __attribute__((ext_vector_type(4))) int   i32x4;
typedef __attribute__((ext_vector_type(4))) unsigned short u16x4;

__device__ __forceinline__ float b2f(unsigned short u){
    unsigned int x = ((unsigned int)u) << 16;
    float f; __builtin_memcpy(&f, &x, 4); return f;
}
__device__ __forceinline__ unsigned short f2b(float f){
    __hip_bfloat16 h = __float2bfloat16(f);
    return *(unsigned short*)&h;
}

// ---------------- D1: fused xcvt (blocks 0..2047) + wcomb (2048..2175) + ws-zero (2176..2200) ----------------

__global__ __launch_bounds__(256) void k_pre(const float* __restrict__ x, unsigned short* __restrict__ xbf,
                                             const float* __restrict__ W1, const float* __restrict__ W2,
                                             const float* __restrict__ Wmu, const float* __restrict__ Wlv,
                                             const float* __restrict__ b1, const float* __restrict__ b2,
                                             unsigned short* __restrict__ WcT, float* __restrict__ cvec,
                                             float* __restrict__ zbase){
    int b = blockIdx.x, t = threadIdx.x;
    if (b < 2048){
        int g = (b*256 + t)*4;
        f32x4 v = *(const f32x4*)(x + g);
        u16x4 o;
        #pragma unroll
        for (int j=0;j<4;j++) o[j] = f2b(v[j]);
        *(u16x4*)(xbf + g) = o;
    } else if (b < 2176){
        int r = (b - 2048)*2 + (t >> 7);    // 0..255
        int j = t & 127;                    // wave-uniform Wsel select
        const float* Wsel = (j < 64) ? Wmu : Wlv;
        int jj = j & 63;
        float acc = 0.f;
        for (int k=0;k<HID1;k++){
            acc += W1[r*HID1+k] * Wsel[k*HID2+jj] + W2[r*HID1+k] * Wsel[(HID1+k)*HID2+jj];
        }
        WcT[(size_t)j*IN_DIM + r] = f2b(acc);
        if (r == 0){
            float c = 0.f;
            for (int k=0;k<HID1;k++){
                c += b1[k]*Wsel[k*HID2+jj] + b2[k]*Wsel[(HID1+k)*HID2+jj];
            }
            cvec[j] = c;
        }
    } else {
        // zero 102400 B of ws (deg + rowPtr + fill): 25 blocks x 256 thr x 16 B
        ((f32x4*)zbase)[(b-2176)*256 + t] = (f32x4){0.f,0.f,0.f,0.f};
    }
}

// ---------------- D2: degree count (4 edges/thread) ----------------

__global__ __launch_bounds__(256) void k_count(const int* __restrict__ ei, int* __restrict__ deg){
    int e4 = (blockIdx.x*256 + threadIdx.x)*4;
    if (e4 >= TOT_EDGES) return;
    if (e4 < N_EDGES){
        i32x4 rr = *(const i32x4*)(ei + e4);
        #pragma unroll
        for (int j=0;j<4;j++) atomicAdd(&deg[rr[j]], 1);
    } else {
        #pragma unroll
        for (int j=0;j<4;j++) atomicAdd(&deg[e4 - N_EDGES + j], 1);
    }
}

// ---------------- D3: fused scan+dinv (block 0) + gemm_u (blocks 1..256, bf16 out) ----------------

__global__ __launch_bounds__(256) void k_scan_gemm(const int* __restrict__ deg, int* __restrict__ rowPtr,
                                                   float* __restrict__ dinv,
                                                   const unsigned short* __restrict__ xbf,
                                                   const unsigned short* __restrict__ WcT,
                                                   unsigned short* __restrict__ Ubf){
    __shared__ int lds[256];
    int t = threadIdx.x;
    if (blockIdx.x == 0){
        int base = t*32;
        const i32x4* dp = (const i32x4*)(deg + base);
        int s = 0;
        #pragma unroll
        for (int k=0;k<8;k++){ i32x4 q = dp[k]; s += q[0]+q[1]+q[2]+q[3]; }
        lds[t] = s;
        __syncthreads();
        for (int off=1; off<256; off<<=1){
            int v = (t >= off) ? lds[t-off] : 0;
            __syncthreads();
            lds[t] += v;
            __syncthreads();
        }
        int run = (t==0) ? 0 : lds[t-1];
        #pragma unroll
        for (int k=0;k<8;k++){
            i32x4 q = dp[k];
            i32x4 rp; f32x4 dv;
            #pragma unroll
            for (int j=0;j<4;j++){
                rp[j] = run;
                dv[j] = (q[j] > 0) ? rsqrtf((float)q[j]) : 0.f;
                run += q[j];
            }
            *(i32x4*)(rowPtr + base + k*4) = rp;
            *(f32x4*)(dinv   + base + k*4) = dv;
        }
        if (t == 255) rowPtr[N_NODES] = run;
    } else {
        // U = x @ Wc via bf16 MFMA. Block tile 32 x 128 (4 waves of 32x32). Output bf16.
        int l  = t & 63;
        int w  = t >> 6;
        int Ibase = (blockIdx.x - 1)*32;
        int Jbase = w*32;
        int lr = l & 15;
        int kg = l >> 4;
        f32x4 acc[2][2];
        #pragma unroll
        for (int mt=0;mt<2;mt++)
            #pragma unroll
            for (int nt=0;nt<2;nt++) acc[mt][nt] = (f32x4){0.f,0.f,0.f,0.f};
        #pragma unroll
        for (int kc=0; kc<IN_DIM/32; kc++){
            bf16x8 a[2], bb[2];
            #pragma unroll
            for (int mt=0;mt<2;mt++)
                a[mt] = *(const bf16x8*)(xbf + (size_t)(Ibase+mt*16+lr)*IN_DIM + kc*32 + kg*8);
            #pragma unroll
            for (int nt=0;nt<2;nt++)
                bb[nt] = *(const bf16x8*)(WcT + (size_t)(Jbase+nt*16+lr)*IN_DIM + kc*32 + kg*8);
            #pragma unroll
            for (int mt=0;mt<2;mt++)
                #pragma unroll
                for (int nt=0;nt<2;nt++)
                    acc[mt][nt] = __builtin_amdgcn_mfma_f32_16x16x32_bf16(a[mt], bb[nt], acc[mt][nt], 0, 0, 0);
        }
        #pragma unroll
        for (int mt=0;mt<2;mt++)
            #pragma unroll
            for (int r=0;r<4;r++){
                int grow = Ibase + mt*16 + kg*4 + r;
                #pragma unroll
                for (int nt=0;nt<2;nt++)
                    Ubf[(size_t)grow*DC + Jbase + nt*16 + lr] = f2b(acc[mt][nt][r]);
            }
    }
}

// ---------------- D4: CSR fill (4 edges/thread) ----------------

__global__ __launch_bounds__(256) void k_fill(const int* __restrict__ ei, const int* __restrict__ rowPtr,
                                              int* __restrict__ fill, int* __restrict__ csr_col){
    int e4 = (blockIdx.x*256 + threadIdx.x)*4;
    if (e4 >= TOT_EDGES) return;
    if (e4 < N_EDGES){
        i32x4 rr = *(const i32x4*)(ei + e4);
        i32x4 cc = *(const i32x4*)(ei + N_EDGES + e4);
        #pragma unroll
        for (int j=0;j<4;j++){
            int pos = rowPtr[rr[j]] + atomicAdd(&fill[rr[j]], 1);
            csr_col[pos] = cc[j];
        }
    } else {
        #pragma unroll
        for (int j=0;j<4;j++){
            int r = e4 - N_EDGES + j;
            int pos = rowPtr[r] + atomicAdd(&fill[r], 1);
            csr_col[pos] = r;
        }
    }
}

// ---------------- D5: SpMM  Tbf = Â * Ubf  (bf16 gathers: 16 lanes x 8 dims, 16 edge-groups) ----------------

__global__ __launch_bounds__(256) void k_spmm(const unsigned short* __restrict__ IN, const int* __restrict__ rowPtr,
                                              const int* __restrict__ csr_col, const float* __restrict__ dinv,
                                              unsigned short* __restrict__ OUT){
    int i = blockIdx.x;
    int tid = threadIdx.x;
    int lane = tid & 15, eg = tid >> 4;
    int beg = rowPtr[i], end = rowPtr[i+1];
    __shared__ int   s_col[128];
    __shared__ float s_w[128];
    __shared__ float s_par[16][DC];
    float acc[8] = {0.f,0.f,0.f,0.f,0.f,0.f,0.f,0.f};
    for (int base = beg; base < end; base += 128){
        int nch  = min(128, end - base);
        int nchp = (nch + 15) & ~15;
        if (tid < 128){
            if (tid < nch){ int c = csr_col[base + tid]; s_col[tid] = c; s_w[tid] = dinv[c]; }
            else if (tid < nchp){ s_col[tid] = 0; s_w[tid] = 0.f; }
        }
        __syncthreads();
        for (int e = eg; e < nchp; e += 16){
            int c = s_col[e]; float wgt = s_w[e];
            bf16x8 v = *(const bf16x8*)(IN + (size_t)c*DC + lane*8);
            #pragma unroll
            for (int j=0;j<8;j++) acc[j] += wgt * b2f((unsigned short)v[j]);
        }
        __syncthreads();
    }
    #pragma unroll
    for (int j=0;j<8;j++) s_par[eg][lane*8+j] = acc[j];
    __syncthreads();
    if (tid < DC){
        float s = 0.f;
        #pragma unroll
        for (int g=0; g<16; g++) s += s_par[g][tid];
        OUT[(size_t)i*DC + tid] = f2b(dinv[i]*s);
    }
}

// ---------------- D6: second SpMM + rank-1 bias + outputs (mu f32, lv f32, mu bf16) ----------------

__global__ __launch_bounds__(256) void k_spmm_out(const unsigned short* __restrict__ T, const int* __restrict__ rowPtr,
                                                  const int* __restrict__ csr_col, const float* __restrict__ dinv,
                                                  const float* __restrict__ cvec,
                                                  const float* __restrict__ bmu, const float* __restrict__ blv,
                                                  float* __restrict__ outMu, float* __restrict__ outLv,
                                                  unsigned short* __restrict__ muBf){
    int i = blockIdx.x;
    int tid = threadIdx.x;
    int lane = tid & 15, eg = tid >> 4;
    int beg = rowPtr[i], end = rowPtr[i+1];
    __shared__ int   s_col[128];
    __shared__ float s_w[128];
    __shared__ float s_par[16][DC];
    __shared__ float s_wred[16];
    float acc[8] = {0.f,0.f,0.f,0.f,0.f,0.f,0.f,0.f};
    float wsum = 0.f;
    for (int base = beg; base < end; base += 128){
        int nch  = min(128, end - base);
        int nchp = (nch + 15) & ~15;
        if (tid < 128){
            if (tid < nch){ int c = csr_col[base + tid]; s_col[tid] = c; s_w[tid] = dinv[c]; }
            else if (tid < nchp){ s_col[tid] = 0; s_w[tid] = 0.f; }
        }
        __syncthreads();
        for (int e = eg; e < nchp; e += 16){
            int c = s_col[e]; float wgt = s_w[e];
            wsum += wgt;
            bf16x8 v = *(const bf16x8*)(T + (size_t)c*DC + lane*8);
            #pragma unroll
            for (int j=0;j<8;j++) acc[j] += wgt * b2f((unsigned short)v[j]);
        }
        __syncthreads();
    }
    #pragma unroll
    for (int j=0;j<8;j++) s_par[eg][lane*8+j] = acc[j];
    if (lane == 0) s_wred[eg] = wsum;
    __syncthreads();
    if (tid < DC){
        float s = 0.f;
        #pragma unroll
        for (int g=0; g<16; g++) s += s_par[g][tid];
        float ws = 0.f;
        #pragma unroll
        for (int g=0; g<16; g++) ws += s_wred[g];
        float di  = dinv[i];
        float sv  = di * ws;                          // (Â·1)_i
        float val = di*s + sv*cvec[tid] + ((tid < 64) ? bmu[tid] : blv[tid-64]);
        if (tid < 64){
            outMu[(size_t)i*HID2 + tid] = val;
            muBf [(size_t)i*HID2 + tid] = f2b(val);
        } else {
            outLv[(size_t)i*HID2 + (tid-64)] = val;
        }
    }
}

// ---------------- D7: adj = sigmoid(mu @ mu^T) via bf16 MFMA, LDS-transposed coalesced epilogue ----------------

__global__ __launch_bounds__(256) void k_adj(const unsigned short* __restrict__ mu, float* __restrict__ adj){
    int t  = threadIdx.x;
    int l  = t & 63;
    int w  = t >> 6;
    int wr = w >> 1, wc = w & 1;
    int Ibase = blockIdx.y*128 + wr*64;
    int Jbase0 = blockIdx.x*128;
    int Jbase = Jbase0 + wc*64;
    int lr = l & 15;
    int kg = l >> 4;

    bf16x8 afr[4][2], bfr[4][2];
    #pragma unroll
    for (int mt=0; mt<4; mt++){
        const unsigned short* p = mu + (size_t)(Ibase + mt*16 + lr)*HID2 + kg*8;
        afr[mt][0] = *(const bf16x8*)(p);
        afr[mt][1] = *(const bf16x8*)(p + 32);
    }
    #pragma unroll
    for (int nt=0; nt<4; nt++){
        const unsigned short* p = mu + (size_t)(Jbase + nt*16 + lr)*HID2 + kg*8;
        bfr[nt][0] = *(const bf16x8*)(p);
        bfr[nt][1] = *(const bf16x8*)(p + 32);
    }

    f32x4 acc[4][4];
    #pragma unroll
    for (int mt=0; mt<4; mt++)
        #pragma unroll
        for (int nt=0; nt<4; nt++)
            acc[mt][nt] = (f32x4){0.f,0.f,0.f,0.f};

    #pragma unroll
    for (int kc=0; kc<2; kc++)
        #pragma unroll
        for (int mt=0; mt<4; mt++)
            #pragma unroll
            for (int nt=0; nt<4; nt++)
                acc[mt][nt] = __builtin_amdgcn_mfma_f32_16x16x32_bf16(afr[mt][kc], bfr[nt][kc], acc[mt][nt], 0, 0, 0);

    // epilogue: two 64-row passes through LDS, plain wide coalesced stores
    __shared__ float tile[64][132];
    int rowBlockBase = blockIdx.y*128;
    #pragma unroll
    for (int p=0; p<2; p++){
        if (wr == p){
            #pragma unroll
            for (int mt=0; mt<4; mt++)
                #pragma unroll
                for (int r=0; r<4; r++){
                    int row_local = mt*16 + kg*4 + r;
                    #pragma unroll
                    for (int nt=0; nt<4; nt++){
                        float v = acc[mt][nt][r];
                        tile[row_local][wc*64 + nt*16 + lr] = 1.f/(1.f + __expf(-v));
                    }
                }
        }
        __syncthreads();
        #pragma unroll
        for (int rep=0; rep<8; rep++){
            int row_r = rep*8 + (t >> 5);
            int col   = (t & 31)*4;
            f32x4 v = *(const f32x4*)&tile[row_r][col];
            int grow = rowBlockBase + p*64 + row_r;
            *(f32x4*)(adj + (size_t)grow*N_NODES + Jbase0 + col) = v;
        }
        __syncthreads();
    }
}

// ---------------- launch ----------------

extern "C" void kernel_launch(void* const* d_in, const int* in_sizes, int n_in,
                              void* d_out, int out_size, void* d_ws, size_t ws_size,
                              hipStream_t stream){
    const float* x   = (const float*)d_in[0];
    const int*   ei  = (const int*)  d_in[1];
    const float* W1  = (const float*)d_in[2];
    const float* b1  = (const float*)d_in[3];
    const float* W2  = (const float*)d_in[4];
    const float* b2  = (const float*)d_in[5];
    const float* Wmu = (const float*)d_in[6];
    const float* bmu = (const float*)d_in[7];
    const float* Wlv = (const float*)d_in[8];
    const float* blv = (const float*)d_in[9];

    char* ws = (char*)d_ws;
    int*   deg    = (int*)  (ws + 0);        // 32768 B
    int*   rowPtr = (int*)  (ws + 32768);    // 8193 ints (+pad)
    int*   fill   = (int*)  (ws + 69632);    // 32768 B, ends at 102400
    float* dinv   = (float*)(ws + 102400);   // 32768 B
    int*   csrcol = (int*)  (ws + 135168);   // 2,129,920 B -> 2,265,088
    unsigned short* WcT = (unsigned short*)(ws + 2265088); // 64 KB -> 2,330,624
    float* cvec   = (float*)(ws + 2330624);  // 512 B -> 2,331,136
    unsigned short* muBf = (unsigned short*)(ws + 2331136); // 1 MB -> 3,379,712
    unsigned short* xbf  = (unsigned short*)(ws + 3379712); // 4 MB -> 7,574,016

    float* adj   = (float*)d_out;
    float* outMu = adj + (size_t)N_NODES*N_NODES;
    float* outLv = outMu + (size_t)N_NODES*HID2;

    // Ubf, Tbf dead before k_adj -> stage inside adj region (268 MB), bf16 (2 MB each)
    unsigned short* Ubf = (unsigned short*)adj;                          // 2 MB
    unsigned short* Tbf = (unsigned short*)((char*)adj + 16*1024*1024);  // disjoint

    k_pre      <<<2201, 256, 0, stream>>>(x, xbf, W1, W2, Wmu, Wlv, b1, b2, WcT, cvec, (float*)ws);
    k_count    <<< 520, 256, 0, stream>>>(ei, deg);
    k_scan_gemm<<< 257, 256, 0, stream>>>(deg, rowPtr, dinv, xbf, WcT, Ubf);
    k_fill     <<< 520, 256, 0, stream>>>(ei, rowPtr, fill, csrcol);
    k_spmm     <<<N_NODES, 256, 0, stream>>>(Ubf, rowPtr, csrcol, dinv, Tbf);
    k_spmm_out <<<N_NODES, 256, 0, stream>>>(Tbf, rowPtr, csrcol, dinv, cvec, bmu, blv,
                                             outMu, outLv, muBf);
    k_adj      <<<dim3(N_NODES/128, N_NODES/128), 256, 0, stream>>>(muBf, adj);
}